// Round 9
// baseline (179.882 us; speedup 1.0000x reference)
//
#include <hip/hip_runtime.h>
#include <hip/hip_bf16.h>

// Sizes fixed by the problem.
#define B_  8
#define T_  2048
#define H_  1024
#define M_  256

typedef __bf16 bf16x8 __attribute__((ext_vector_type(8)));
typedef float  f32x4  __attribute__((ext_vector_type(4)));
typedef unsigned short us4 __attribute__((ext_vector_type(4)));
typedef unsigned short us8 __attribute__((ext_vector_type(8)));

__device__ inline unsigned short f2bf(float f) {
    unsigned int u = __builtin_bit_cast(unsigned int, f);
    return (unsigned short)((u + 0x7FFFu + ((u >> 16) & 1u)) >> 16);
}
__device__ inline float bf2f(unsigned short u) {
    unsigned int x = ((unsigned int)u) << 16;
    return __builtin_bit_cast(float, x);
}

// ---------------------------------------------------------------------------
// K_prep: fused {basis cast, coupling transpose-cast, bias GEMV}.
// grid 1280 x 256
__global__ void k_prep(const float* __restrict__ basis, const float* __restrict__ cpl,
                       const float* __restrict__ W, const float* __restrict__ re,
                       const float* __restrict__ im, const float* __restrict__ g_srg,
                       unsigned short* __restrict__ basisB, unsigned short* __restrict__ cplT,
                       float* __restrict__ bias)
{
    int blk = blockIdx.x;
    int tid = threadIdx.x;
    if (blk < 1024) {
        size_t i = ((size_t)blk * 256 + tid) * 8;
        float4 a = *(const float4*)&basis[i];
        float4 b = *(const float4*)&basis[i + 4];
        us8 o = { f2bf(a.x), f2bf(a.y), f2bf(a.z), f2bf(a.w),
                  f2bf(b.x), f2bf(b.y), f2bf(b.z), f2bf(b.w) };
        *(us8*)&basisB[i] = o;
    } else if (blk < 1152) {
        int idx = blk - 1024;
        int x = idx & 3, y = (idx >> 2) & 3, b = idx >> 4;
        int r0 = x * 64, c0 = y * 64;
        __shared__ float t[64][65];
        #pragma unroll
        for (int i = 0; i < 4; ++i) {
            int u = tid + i * 256;
            int r = u >> 4, c4 = (u & 15) * 4;
            float4 v = *(const float4*)&cpl[((size_t)(b * M_ + r0 + r)) * M_ + c0 + c4];
            t[r][c4] = v.x; t[r][c4 + 1] = v.y; t[r][c4 + 2] = v.z; t[r][c4 + 3] = v.w;
        }
        __syncthreads();
        #pragma unroll
        for (int i = 0; i < 4; ++i) {
            int u = tid + i * 256;
            int m = u >> 4, r4 = (u & 15) * 4;
            us4 o = { f2bf(t[r4][m]), f2bf(t[r4 + 1][m]), f2bf(t[r4 + 2][m]), f2bf(t[r4 + 3][m]) };
            *(us4*)&cplT[((size_t)(b * M_ + c0 + m)) * M_ + r0 + r4] = o;
        }
    } else {
        int idx = blk - 1152;
        int b = idx & 7, h0 = (idx >> 3) * 64;
        int lane = tid & 63, w = tid >> 6;
        int h = h0 + lane;
        float acc = 0.f;
        #pragma unroll 4
        for (int m = w * 64; m < w * 64 + 64; ++m) {
            float rv = re[b * M_ + m], iv = im[b * M_ + m];
            acc += rv * W[(size_t)m * H_ + h] + iv * W[(size_t)(M_ + m) * H_ + h];
        }
        __shared__ float sh[4][64];
        sh[w][lane] = acc;
        __syncthreads();
        if (w == 0)
            bias[b * H_ + h] = g_srg[0] * (sh[0][lane] + sh[1][lane] + sh[2][lane] + sh[3][lane]);
    }
}

// ---------------------------------------------------------------------------
// K1b: b2T[b][n][h] = sum_mp cplT[b][n][mp] * basisB[b][h][mp]   (bf16 MFMA GEMM)
__global__ __launch_bounds__(256) void k_b2(const unsigned short* __restrict__ cplT,
                                            const unsigned short* __restrict__ basisB,
                                            unsigned short* __restrict__ b2T)
{
    const int b = blockIdx.z;
    const int n0 = blockIdx.x * 64;
    const int h0 = blockIdx.y * 128;
    const int tid = threadIdx.x;
    const int lane = tid & 63, w = tid >> 6;

    __shared__ __align__(16) unsigned short As[64][72];
    __shared__ __align__(16) unsigned short Bs[128][72];

    const unsigned short* Ab = cplT + (size_t)(b * M_ + n0) * M_;
    const unsigned short* Bb = basisB + (size_t)(b * H_ + h0) * M_;

    f32x4 acc[4][2];
    #pragma unroll
    for (int i = 0; i < 4; ++i) { acc[i][0] = (f32x4){0,0,0,0}; acc[i][1] = (f32x4){0,0,0,0}; }

    const int rsel = lane & 15;
    const int kgrp = (lane >> 4) * 8;

    for (int k0 = 0; k0 < M_; k0 += 64) {
        #pragma unroll
        for (int i = 0; i < 2; ++i) {
            int u = tid + i * 256;
            int r = u >> 3, c8 = (u & 7) * 8;
            *(us8*)&As[r][c8] = *(const us8*)&Ab[(size_t)r * M_ + k0 + c8];
        }
        #pragma unroll
        for (int i = 0; i < 4; ++i) {
            int u = tid + i * 256;
            int r = u >> 3, c8 = (u & 7) * 8;
            *(us8*)&Bs[r][c8] = *(const us8*)&Bb[(size_t)r * M_ + k0 + c8];
        }
        __syncthreads();
        #pragma unroll
        for (int kk = 0; kk < 2; ++kk) {
            const int kb = kk * 32 + kgrp;
            bf16x8 af[4], bfr[2];
            #pragma unroll
            for (int mi = 0; mi < 4; ++mi) af[mi] = *(const bf16x8*)&As[mi * 16 + rsel][kb];
            #pragma unroll
            for (int ni = 0; ni < 2; ++ni) bfr[ni] = *(const bf16x8*)&Bs[w * 32 + ni * 16 + rsel][kb];
            #pragma unroll
            for (int mi = 0; mi < 4; ++mi)
                #pragma unroll
                for (int ni = 0; ni < 2; ++ni)
                    acc[mi][ni] = __builtin_amdgcn_mfma_f32_16x16x32_bf16(af[mi], bfr[ni], acc[mi][ni], 0, 0, 0);
        }
        __syncthreads();
    }

    unsigned short* ob = b2T + (size_t)(b * M_ + n0) * H_ + h0;
    const int rbase = (lane >> 4) * 4;
    #pragma unroll
    for (int mi = 0; mi < 4; ++mi)
        #pragma unroll
        for (int ni = 0; ni < 2; ++ni)
            #pragma unroll
            for (int r = 0; r < 4; ++r)
                ob[(size_t)(mi * 16 + rbase + r) * H_ + w * 32 + ni * 16 + rsel] = f2bf(acc[mi][ni][r]);
}

// ---------------------------------------------------------------------------
// K_gate: pure streaming with deep ILP. 16 f32 elems/thread: 12 stream float4
// loads + 4 bias float4 loads all in flight, then compute, then 2 x 32B store.
// comb16[b][t][h] = bf16(hs + bu*inc + td*tdn + bias[b][h])
// grid 4096 x 256, batch-per-XCD (blk&7).
__global__ __launch_bounds__(256) void k_gate(
    const float* __restrict__ hs, const float* __restrict__ inc, const float* __restrict__ tdn,
    const float* __restrict__ bias, const float* __restrict__ g_bu, const float* __restrict__ g_td,
    unsigned short* __restrict__ comb)
{
    const int blk = blockIdx.x;
    const int b = blk & 7;
    const size_t e = ((size_t)(blk >> 3) * 256 + threadIdx.x) * 16;  // in-batch elem
    const int h = (int)(e & (H_ - 1));
    const size_t g = (size_t)b * ((size_t)T_ * H_) + e;
    const float bug = g_bu[0], tdg = g_td[0];

    f32x4 a0 = *(const f32x4*)(hs + g),      a1 = *(const f32x4*)(hs + g + 4);
    f32x4 a2 = *(const f32x4*)(hs + g + 8),  a3 = *(const f32x4*)(hs + g + 12);
    f32x4 i0 = *(const f32x4*)(inc + g),     i1 = *(const f32x4*)(inc + g + 4);
    f32x4 i2 = *(const f32x4*)(inc + g + 8), i3 = *(const f32x4*)(inc + g + 12);
    f32x4 d0 = *(const f32x4*)(tdn + g),     d1 = *(const f32x4*)(tdn + g + 4);
    f32x4 d2 = *(const f32x4*)(tdn + g + 8), d3 = *(const f32x4*)(tdn + g + 12);
    f32x4 b0 = *(const f32x4*)(bias + b * H_ + h);
    f32x4 b1 = *(const f32x4*)(bias + b * H_ + h + 4);
    f32x4 b2 = *(const f32x4*)(bias + b * H_ + h + 8);
    f32x4 b3 = *(const f32x4*)(bias + b * H_ + h + 12);

    f32x4 c0 = a0 + bug * i0 + tdg * d0 + b0;
    f32x4 c1 = a1 + bug * i1 + tdg * d1 + b1;
    f32x4 c2 = a2 + bug * i2 + tdg * d2 + b2;
    f32x4 c3 = a3 + bug * i3 + tdg * d3 + b3;

    us8 o0 = { f2bf(c0[0]), f2bf(c0[1]), f2bf(c0[2]), f2bf(c0[3]),
               f2bf(c1[0]), f2bf(c1[1]), f2bf(c1[2]), f2bf(c1[3]) };
    us8 o1 = { f2bf(c2[0]), f2bf(c2[1]), f2bf(c2[2]), f2bf(c2[3]),
               f2bf(c3[0]), f2bf(c3[1]), f2bf(c3[2]), f2bf(c3[3]) };
    *(us8*)&comb[g]     = o0;
    *(us8*)&comb[g + 8] = o1;
}

// ---------------------------------------------------------------------------
// K2: alpha16 = comb16 @ b2. Full-K A tile (32x1024 bf16, 64KB LDS, XOR-swizzle),
// ONE barrier; B gathered from XCD-resident b2T. 4 waves (m-quarter each),
// grid 512 flat (batch-per-XCD), 2 blocks/CU.
__global__ __launch_bounds__(256, 2) void k_alpha(
    const unsigned short* __restrict__ comb, const unsigned short* __restrict__ b2T,
    unsigned short* __restrict__ alpha16)
{
    const int flat = blockIdx.x;
    const int b = flat & 7;
    const int t0 = (flat >> 3) * 32;
    const int tid = threadIdx.x;
    const int lane = tid & 63, wid = tid >> 6;

    __shared__ __align__(16) unsigned short As[32 * 1024];   // 64 KB, swizzled

    const unsigned short* src = comb + ((size_t)(b * T_) + t0) * H_;

    // stage full A tile: 16 iters x 256 thr x us8 = 32768 elems (stride 2048)
    #pragma unroll
    for (int i = 0; i < 16; ++i) {
        int e = i * 2048 + tid * 8;
        int row = e >> 10;
        int col = e & 1023;
        int sw = (((col >> 3) ^ (row & 7)) << 3);
        *(us8*)&As[row * 1024 + sw] = *(const us8*)&src[e];
    }
    __syncthreads();

    const int rsel = lane & 15;
    const int kgo = (lane >> 4) * 8;
    const int rswz = rsel & 7;
    const unsigned short* As0 = &As[rsel * 1024];
    const unsigned short* As1 = &As[(16 + rsel) * 1024];
    const unsigned short* Bb = b2T + ((size_t)(b * M_) + wid * 64 + rsel) * H_ + kgo;

    f32x4 acc[2][4];
    #pragma unroll
    for (int i = 0; i < 2; ++i)
        #pragma unroll
        for (int j = 0; j < 4; ++j)
            acc[i][j] = (f32x4){0.f, 0.f, 0.f, 0.f};

    #pragma unroll 4
    for (int kc = 0; kc < 32; ++kc) {
        int cA = kc * 32 + kgo;
        int sw = ((((cA) >> 3) ^ rswz) << 3);
        bf16x8 af0 = *(const bf16x8*)&As0[sw];
        bf16x8 af1 = *(const bf16x8*)&As1[sw];
        #pragma unroll
        for (int ni = 0; ni < 4; ++ni) {
            bf16x8 bv = *(const bf16x8*)(Bb + (size_t)ni * (16 * H_) + kc * 32);
            acc[0][ni] = __builtin_amdgcn_mfma_f32_16x16x32_bf16(af0, bv, acc[0][ni], 0, 0, 0);
            acc[1][ni] = __builtin_amdgcn_mfma_f32_16x16x32_bf16(af1, bv, acc[1][ni], 0, 0, 0);
        }
    }

    unsigned short* ab = alpha16 + ((size_t)(b * T_) + t0) * M_ + wid * 64;
    const int rbase = (lane >> 4) * 4;
    #pragma unroll
    for (int mi = 0; mi < 2; ++mi)
        #pragma unroll
        for (int ni = 0; ni < 4; ++ni)
            #pragma unroll
            for (int r = 0; r < 4; ++r)
                ab[(size_t)(mi * 16 + rbase + r) * M_ + ni * 16 + rsel] = f2bf(acc[mi][ni][r]);
}

// ---------------------------------------------------------------------------
// K3: chunked-parallel scan, chunk=32, halo=96 (gamma^96 ~ 4e-5)
// grid 512 flat (batch-per-XCD), block 256 (= m)
__global__ void k_scan(const unsigned short* __restrict__ alpha16, const float* __restrict__ tape_re,
                       const float* __restrict__ g_gr, const float* __restrict__ g_br,
                       unsigned short* __restrict__ cbuf)
{
    int flat = blockIdx.x;
    int b = flat & 7, chunk = flat >> 3;
    int m = threadIdx.x;
    float graw = g_gr[0], braw = g_br[0];
    float gamma = 1.f / (1.f + __expf(-graw));
    float beta  = log1pf(__expf(braw));
    int t0 = chunk * 32;
    int th = (t0 >= 96) ? (t0 - 96) : 0;
    float s = tape_re[b * M_ + m];
    if (th > 0) s *= __powf(gamma, (float)th);
    const unsigned short* ab = alpha16 + (size_t)b * T_ * M_ + m;
    unsigned short* cb = cbuf + (size_t)b * T_ * M_ + m;
    #pragma unroll 4
    for (int t = th; t < t0 + 32; ++t) {
        float a = bf2f(ab[(size_t)t * M_]);
        s = gamma * s + beta * a;
        if (t >= t0) cb[(size_t)t * M_] = f2bf(a * s);
    }
}

// ---------------------------------------------------------------------------
// K4: y = c @ basis^T. Same single-barrier full-K template: A = cbuf tile
// 32x256 in LDS (16KB, XOR-swizzle), B = basisB gathered from XCD-resident L2.
// 8 waves (h-slice of 128 each), grid 512 flat, 2 blocks/CU. Write-bound.
__global__ __launch_bounds__(512, 4) void k_y(const unsigned short* __restrict__ cbuf,
                                              const unsigned short* __restrict__ basisB,
                                              float* __restrict__ out)
{
    const int flat = blockIdx.x;
    const int b = flat & 7;
    const int t0 = (flat >> 3) * 32;
    const int tid = threadIdx.x;
    const int lane = tid & 63, wid = tid >> 6;

    __shared__ __align__(16) unsigned short As[32 * 256];    // 16 KB, swizzled

    const unsigned short* src = cbuf + ((size_t)(b * T_) + t0) * M_;
    #pragma unroll
    for (int i = 0; i < 2; ++i) {
        int e = i * 4096 + tid * 8;          // 512 thr x 8 = 4096 per iter
        int row = e >> 8;
        int col = e & 255;
        int sw = (((col >> 3) ^ (row & 7)) << 3);
        *(us8*)&As[row * 256 + sw] = *(const us8*)&src[e];
    }
    __syncthreads();

    const int rsel = lane & 15;
    const int kgo = (lane >> 4) * 8;
    const int rswz = rsel & 7;
    const unsigned short* As0 = &As[rsel * 256];
    const unsigned short* As1 = &As[(16 + rsel) * 256];
    const unsigned short* Bh = basisB + ((size_t)(b * H_) + wid * 128 + rsel) * M_ + kgo;

    f32x4 acc[2][8];
    #pragma unroll
    for (int i = 0; i < 2; ++i)
        #pragma unroll
        for (int j = 0; j < 8; ++j)
            acc[i][j] = (f32x4){0.f, 0.f, 0.f, 0.f};

    #pragma unroll 2
    for (int kc = 0; kc < 8; ++kc) {
        int cA = kc * 32 + kgo;
        int sw = ((((cA) >> 3) ^ rswz) << 3);
        bf16x8 af0 = *(const bf16x8*)&As0[sw];
        bf16x8 af1 = *(const bf16x8*)&As1[sw];
        #pragma unroll
        for (int ni = 0; ni < 8; ++ni) {
            bf16x8 bv = *(const bf16x8*)(Bh + (size_t)ni * (16 * M_) + kc * 32);
            acc[0][ni] = __builtin_amdgcn_mfma_f32_16x16x32_bf16(af0, bv, acc[0][ni], 0, 0, 0);
            acc[1][ni] = __builtin_amdgcn_mfma_f32_16x16x32_bf16(af1, bv, acc[1][ni], 0, 0, 0);
        }
    }

    float* ob = out + ((size_t)(b * T_) + t0) * H_ + wid * 128;
    const int rbase = (lane >> 4) * 4;
    #pragma unroll
    for (int mi = 0; mi < 2; ++mi)
        #pragma unroll
        for (int ni = 0; ni < 8; ++ni)
            #pragma unroll
            for (int r = 0; r < 4; ++r)
                ob[(size_t)(mi * 16 + rbase + r) * H_ + ni * 16 + rsel] = acc[mi][ni][r];
}

// ---------------------------------------------------------------------------
extern "C" void kernel_launch(void* const* d_in, const int* in_sizes, int n_in,
                              void* d_out, int out_size, void* d_ws, size_t ws_size,
                              hipStream_t stream)
{
    const float* hs   = (const float*)d_in[0];
    const float* inc  = (const float*)d_in[1];
    const float* tdn  = (const float*)d_in[2];
    const float* basis= (const float*)d_in[3];
    const float* cpl  = (const float*)d_in[4];
    const float* W    = (const float*)d_in[5];
    const float* t_re = (const float*)d_in[6];
    const float* t_im = (const float*)d_in[7];
    const float* g_bu = (const float*)d_in[8];
    const float* g_td = (const float*)d_in[9];
    const float* g_sr = (const float*)d_in[10];
    const float* g_gr = (const float*)d_in[11];
    const float* g_br = (const float*)d_in[12];
    float* out = (float*)d_out;

    char* ws = (char*)d_ws;
    float*          bias   = (float*)(ws);                                    // 64 KB slot
    unsigned short* basisB = (unsigned short*)(ws + (1u << 16));              // 4 MB
    unsigned short* cplT   = (unsigned short*)(ws + (1u << 16) + (4u << 20)); // 1 MB
    unsigned short* b2T    = (unsigned short*)(ws + (1u << 16) + (5u << 20)); // 4 MB
    unsigned short* alpha16= (unsigned short*)(ws + (1u << 16) + (9u << 20)); // 8 MB
    unsigned short* cbuf   = (unsigned short*)(ws + (1u << 16) + (17u << 20));// 8 MB

    // comb16 (32 MB bf16) lives in d_out: dead before k_y overwrites out.
    unsigned short* comb   = (unsigned short*)d_out;

    k_prep <<<dim3(1280),                  dim3(256), 0, stream>>>(basis, cpl, W, t_re, t_im, g_sr, basisB, cplT, bias);
    k_b2   <<<dim3(M_ / 64, H_ / 128, B_), dim3(256), 0, stream>>>(cplT, basisB, b2T);
    k_gate <<<dim3(4096),                  dim3(256), 0, stream>>>(hs, inc, tdn, bias, g_bu, g_td, comb);
    k_alpha<<<dim3(512),                   dim3(256), 0, stream>>>(comb, b2T, alpha16);
    k_scan <<<dim3(512),                   dim3(256), 0, stream>>>(alpha16, t_re, g_gr, g_br, cbuf);
    k_y    <<<dim3(512),                   dim3(512), 0, stream>>>(cbuf, basisB, out);
}

// Round 10
// 164.140 us; speedup vs baseline: 1.0959x; 1.0959x over previous
//
#include <hip/hip_runtime.h>
#include <hip/hip_bf16.h>

// Sizes fixed by the problem.
#define B_  8
#define T_  2048
#define H_  1024
#define M_  256

typedef __bf16 bf16x8 __attribute__((ext_vector_type(8)));
typedef float  f32x4  __attribute__((ext_vector_type(4)));
typedef unsigned short us4 __attribute__((ext_vector_type(4)));
typedef unsigned short us8 __attribute__((ext_vector_type(8)));

__device__ inline unsigned short f2bf(float f) {
    unsigned int u = __builtin_bit_cast(unsigned int, f);
    return (unsigned short)((u + 0x7FFFu + ((u >> 16) & 1u)) >> 16);
}
__device__ inline float bf2f(unsigned short u) {
    unsigned int x = ((unsigned int)u) << 16;
    return __builtin_bit_cast(float, x);
}

// ---------------------------------------------------------------------------
// K_prep: fused {basis cast, coupling transpose-cast, bias GEMV}.
// grid 1280 x 256
__global__ void k_prep(const float* __restrict__ basis, const float* __restrict__ cpl,
                       const float* __restrict__ W, const float* __restrict__ re,
                       const float* __restrict__ im, const float* __restrict__ g_srg,
                       unsigned short* __restrict__ basisB, unsigned short* __restrict__ cplT,
                       float* __restrict__ bias)
{
    int blk = blockIdx.x;
    int tid = threadIdx.x;
    if (blk < 1024) {
        size_t i = ((size_t)blk * 256 + tid) * 8;
        float4 a = *(const float4*)&basis[i];
        float4 b = *(const float4*)&basis[i + 4];
        us8 o = { f2bf(a.x), f2bf(a.y), f2bf(a.z), f2bf(a.w),
                  f2bf(b.x), f2bf(b.y), f2bf(b.z), f2bf(b.w) };
        *(us8*)&basisB[i] = o;
    } else if (blk < 1152) {
        int idx = blk - 1024;
        int x = idx & 3, y = (idx >> 2) & 3, b = idx >> 4;
        int r0 = x * 64, c0 = y * 64;
        __shared__ float t[64][65];
        #pragma unroll
        for (int i = 0; i < 4; ++i) {
            int u = tid + i * 256;
            int r = u >> 4, c4 = (u & 15) * 4;
            float4 v = *(const float4*)&cpl[((size_t)(b * M_ + r0 + r)) * M_ + c0 + c4];
            t[r][c4] = v.x; t[r][c4 + 1] = v.y; t[r][c4 + 2] = v.z; t[r][c4 + 3] = v.w;
        }
        __syncthreads();
        #pragma unroll
        for (int i = 0; i < 4; ++i) {
            int u = tid + i * 256;
            int m = u >> 4, r4 = (u & 15) * 4;
            us4 o = { f2bf(t[r4][m]), f2bf(t[r4 + 1][m]), f2bf(t[r4 + 2][m]), f2bf(t[r4 + 3][m]) };
            *(us4*)&cplT[((size_t)(b * M_ + c0 + m)) * M_ + r0 + r4] = o;
        }
    } else {
        int idx = blk - 1152;
        int b = idx & 7, h0 = (idx >> 3) * 64;
        int lane = tid & 63, w = tid >> 6;
        int h = h0 + lane;
        float acc = 0.f;
        #pragma unroll 4
        for (int m = w * 64; m < w * 64 + 64; ++m) {
            float rv = re[b * M_ + m], iv = im[b * M_ + m];
            acc += rv * W[(size_t)m * H_ + h] + iv * W[(size_t)(M_ + m) * H_ + h];
        }
        __shared__ float sh[4][64];
        sh[w][lane] = acc;
        __syncthreads();
        if (w == 0)
            bias[b * H_ + h] = g_srg[0] * (sh[0][lane] + sh[1][lane] + sh[2][lane] + sh[3][lane]);
    }
}

// ---------------------------------------------------------------------------
// K1b: b2T[b][n][h] = sum_mp cplT[b][n][mp] * basisB[b][h][mp]   (bf16 MFMA GEMM)
__global__ __launch_bounds__(256) void k_b2(const unsigned short* __restrict__ cplT,
                                            const unsigned short* __restrict__ basisB,
                                            unsigned short* __restrict__ b2T)
{
    const int b = blockIdx.z;
    const int n0 = blockIdx.x * 64;
    const int h0 = blockIdx.y * 128;
    const int tid = threadIdx.x;
    const int lane = tid & 63, w = tid >> 6;

    __shared__ __align__(16) unsigned short As[64][72];
    __shared__ __align__(16) unsigned short Bs[128][72];

    const unsigned short* Ab = cplT + (size_t)(b * M_ + n0) * M_;
    const unsigned short* Bb = basisB + (size_t)(b * H_ + h0) * M_;

    f32x4 acc[4][2];
    #pragma unroll
    for (int i = 0; i < 4; ++i) { acc[i][0] = (f32x4){0,0,0,0}; acc[i][1] = (f32x4){0,0,0,0}; }

    const int rsel = lane & 15;
    const int kgrp = (lane >> 4) * 8;

    for (int k0 = 0; k0 < M_; k0 += 64) {
        #pragma unroll
        for (int i = 0; i < 2; ++i) {
            int u = tid + i * 256;
            int r = u >> 3, c8 = (u & 7) * 8;
            *(us8*)&As[r][c8] = *(const us8*)&Ab[(size_t)r * M_ + k0 + c8];
        }
        #pragma unroll
        for (int i = 0; i < 4; ++i) {
            int u = tid + i * 256;
            int r = u >> 3, c8 = (u & 7) * 8;
            *(us8*)&Bs[r][c8] = *(const us8*)&Bb[(size_t)r * M_ + k0 + c8];
        }
        __syncthreads();
        #pragma unroll
        for (int kk = 0; kk < 2; ++kk) {
            const int kb = kk * 32 + kgrp;
            bf16x8 af[4], bfr[2];
            #pragma unroll
            for (int mi = 0; mi < 4; ++mi) af[mi] = *(const bf16x8*)&As[mi * 16 + rsel][kb];
            #pragma unroll
            for (int ni = 0; ni < 2; ++ni) bfr[ni] = *(const bf16x8*)&Bs[w * 32 + ni * 16 + rsel][kb];
            #pragma unroll
            for (int mi = 0; mi < 4; ++mi)
                #pragma unroll
                for (int ni = 0; ni < 2; ++ni)
                    acc[mi][ni] = __builtin_amdgcn_mfma_f32_16x16x32_bf16(af[mi], bfr[ni], acc[mi][ni], 0, 0, 0);
        }
        __syncthreads();
    }

    unsigned short* ob = b2T + (size_t)(b * M_ + n0) * H_ + h0;
    const int rbase = (lane >> 4) * 4;
    #pragma unroll
    for (int mi = 0; mi < 4; ++mi)
        #pragma unroll
        for (int ni = 0; ni < 2; ++ni)
            #pragma unroll
            for (int r = 0; r < 4; ++r)
                ob[(size_t)(mi * 16 + rbase + r) * H_ + w * 32 + ni * 16 + rsel] = f2bf(acc[mi][ni][r]);
}

// ---------------------------------------------------------------------------
// K2 (FUSED gate+alpha): alpha16 = bf16(hs + bu*inc + td*tdn + bias) @ b2.
// Stage phase: 32 iters, one 1024-col row per iter; thread owns 4 cols
// (coalesced float4 per stream); gate in-register; bias loaded ONCE (col
// fixed per thread); write us4 to XOR-swizzled 64KB LDS. ONE barrier.
// MFMA phase: A from LDS, B gathered from XCD-resident b2T (batch = blk&7).
// grid 512 flat, 256 thr (4 waves = m-quarters), 2 blocks/CU.
__global__ __launch_bounds__(256, 2) void k_alpha(
    const float* __restrict__ hs, const float* __restrict__ inc, const float* __restrict__ tdn,
    const float* __restrict__ bias, const float* __restrict__ g_bu, const float* __restrict__ g_td,
    const unsigned short* __restrict__ b2T, unsigned short* __restrict__ alpha16)
{
    const int flat = blockIdx.x;
    const int b = flat & 7;
    const int t0 = (flat >> 3) * 32;
    const int tid = threadIdx.x;
    const int lane = tid & 63, wid = tid >> 6;

    __shared__ __align__(16) unsigned short As[32 * 1024];   // 64 KB, swizzled

    const float bug = g_bu[0], tdg = g_td[0];
    const int col = tid * 4;                  // 0..1020, fixed per thread
    const size_t rb = ((size_t)(b * T_) + t0) * H_ + col;
    const float* hs0 = hs + rb;
    const float* in0 = inc + rb;
    const float* td0 = tdn + rb;
    f32x4 bi = *(const f32x4*)(bias + b * H_ + col);   // loaded once

    const int swc = (((col >> 3) ^ 0) << 3) | (col & 7);  // col part; row XOR applied per iter

    #pragma unroll 4
    for (int row = 0; row < 32; ++row) {
        f32x4 a = *(const f32x4*)(hs0 + (size_t)row * H_);
        f32x4 e = *(const f32x4*)(in0 + (size_t)row * H_);
        f32x4 d = *(const f32x4*)(td0 + (size_t)row * H_);
        f32x4 c = a + bug * e + tdg * d + bi;
        us4 o = { f2bf(c[0]), f2bf(c[1]), f2bf(c[2]), f2bf(c[3]) };
        int sw = ((((col >> 3) ^ (row & 7)) << 3) | (col & 7));
        *(us4*)&As[row * 1024 + sw] = o;
    }
    (void)swc;
    __syncthreads();

    const int rsel = lane & 15;
    const int kgo = (lane >> 4) * 8;
    const int rswz = rsel & 7;
    const unsigned short* As0 = &As[rsel * 1024];
    const unsigned short* As1 = &As[(16 + rsel) * 1024];
    const unsigned short* Bb = b2T + ((size_t)(b * M_) + wid * 64 + rsel) * H_ + kgo;

    f32x4 acc[2][4];
    #pragma unroll
    for (int i = 0; i < 2; ++i)
        #pragma unroll
        for (int j = 0; j < 4; ++j)
            acc[i][j] = (f32x4){0.f, 0.f, 0.f, 0.f};

    #pragma unroll 4
    for (int kc = 0; kc < 32; ++kc) {
        int cA = kc * 32 + kgo;
        int sw = ((((cA) >> 3) ^ rswz) << 3);
        bf16x8 af0 = *(const bf16x8*)&As0[sw];
        bf16x8 af1 = *(const bf16x8*)&As1[sw];
        #pragma unroll
        for (int ni = 0; ni < 4; ++ni) {
            bf16x8 bv = *(const bf16x8*)(Bb + (size_t)ni * (16 * H_) + kc * 32);
            acc[0][ni] = __builtin_amdgcn_mfma_f32_16x16x32_bf16(af0, bv, acc[0][ni], 0, 0, 0);
            acc[1][ni] = __builtin_amdgcn_mfma_f32_16x16x32_bf16(af1, bv, acc[1][ni], 0, 0, 0);
        }
    }

    unsigned short* ab = alpha16 + ((size_t)(b * T_) + t0) * M_ + wid * 64;
    const int rbase = (lane >> 4) * 4;
    #pragma unroll
    for (int mi = 0; mi < 2; ++mi)
        #pragma unroll
        for (int ni = 0; ni < 4; ++ni)
            #pragma unroll
            for (int r = 0; r < 4; ++r)
                ab[(size_t)(mi * 16 + rbase + r) * M_ + ni * 16 + rsel] = f2bf(acc[mi][ni][r]);
}

// ---------------------------------------------------------------------------
// K3: chunked-parallel scan, chunk=64, halo=96 (gamma^96 ~ 4e-5)
// grid 256 flat (batch-per-XCD), block 256 (= m)
__global__ void k_scan(const unsigned short* __restrict__ alpha16, const float* __restrict__ tape_re,
                       const float* __restrict__ g_gr, const float* __restrict__ g_br,
                       unsigned short* __restrict__ cbuf)
{
    int flat = blockIdx.x;
    int b = flat & 7, chunk = flat >> 3;
    int m = threadIdx.x;
    float graw = g_gr[0], braw = g_br[0];
    float gamma = 1.f / (1.f + __expf(-graw));
    float beta  = log1pf(__expf(braw));
    int t0 = chunk * 64;
    int th = (t0 >= 96) ? (t0 - 96) : 0;
    float s = tape_re[b * M_ + m];
    if (th > 0) s *= __powf(gamma, (float)th);
    const unsigned short* ab = alpha16 + (size_t)b * T_ * M_ + m;
    unsigned short* cb = cbuf + (size_t)b * T_ * M_ + m;
    #pragma unroll 4
    for (int t = th; t < t0 + 64; ++t) {
        float a = bf2f(ab[(size_t)t * M_]);
        s = gamma * s + beta * a;
        if (t >= t0) cb[(size_t)t * M_] = f2bf(a * s);
    }
}

// ---------------------------------------------------------------------------
// K4: y = c @ basis^T. Single-barrier full-K template: A = cbuf tile
// 32x256 in LDS (16KB, XOR-swizzle), B = basisB gathered from XCD-resident L2.
// 8 waves (h-slice of 128 each), grid 512 flat, 2 blocks/CU. Write-bound.
__global__ __launch_bounds__(512, 4) void k_y(const unsigned short* __restrict__ cbuf,
                                              const unsigned short* __restrict__ basisB,
                                              float* __restrict__ out)
{
    const int flat = blockIdx.x;
    const int b = flat & 7;
    const int t0 = (flat >> 3) * 32;
    const int tid = threadIdx.x;
    const int lane = tid & 63, wid = tid >> 6;

    __shared__ __align__(16) unsigned short As[32 * 256];    // 16 KB, swizzled

    const unsigned short* src = cbuf + ((size_t)(b * T_) + t0) * M_;
    #pragma unroll
    for (int i = 0; i < 2; ++i) {
        int e = i * 4096 + tid * 8;          // 512 thr x 8 = 4096 per iter
        int row = e >> 8;
        int col = e & 255;
        int sw = (((col >> 3) ^ (row & 7)) << 3);
        *(us8*)&As[row * 256 + sw] = *(const us8*)&src[e];
    }
    __syncthreads();

    const int rsel = lane & 15;
    const int kgo = (lane >> 4) * 8;
    const int rswz = rsel & 7;
    const unsigned short* As0 = &As[rsel * 256];
    const unsigned short* As1 = &As[(16 + rsel) * 256];
    const unsigned short* Bh = basisB + ((size_t)(b * H_) + wid * 128 + rsel) * M_ + kgo;

    f32x4 acc[2][8];
    #pragma unroll
    for (int i = 0; i < 2; ++i)
        #pragma unroll
        for (int j = 0; j < 8; ++j)
            acc[i][j] = (f32x4){0.f, 0.f, 0.f, 0.f};

    #pragma unroll 2
    for (int kc = 0; kc < 8; ++kc) {
        int cA = kc * 32 + kgo;
        int sw = ((((cA) >> 3) ^ rswz) << 3);
        bf16x8 af0 = *(const bf16x8*)&As0[sw];
        bf16x8 af1 = *(const bf16x8*)&As1[sw];
        #pragma unroll
        for (int ni = 0; ni < 8; ++ni) {
            bf16x8 bv = *(const bf16x8*)(Bh + (size_t)ni * (16 * M_) + kc * 32);
            acc[0][ni] = __builtin_amdgcn_mfma_f32_16x16x32_bf16(af0, bv, acc[0][ni], 0, 0, 0);
            acc[1][ni] = __builtin_amdgcn_mfma_f32_16x16x32_bf16(af1, bv, acc[1][ni], 0, 0, 0);
        }
    }

    float* ob = out + ((size_t)(b * T_) + t0) * H_ + wid * 128;
    const int rbase = (lane >> 4) * 4;
    #pragma unroll
    for (int mi = 0; mi < 2; ++mi)
        #pragma unroll
        for (int ni = 0; ni < 8; ++ni)
            #pragma unroll
            for (int r = 0; r < 4; ++r)
                ob[(size_t)(mi * 16 + rbase + r) * H_ + ni * 16 + rsel] = acc[mi][ni][r];
}

// ---------------------------------------------------------------------------
extern "C" void kernel_launch(void* const* d_in, const int* in_sizes, int n_in,
                              void* d_out, int out_size, void* d_ws, size_t ws_size,
                              hipStream_t stream)
{
    const float* hs   = (const float*)d_in[0];
    const float* inc  = (const float*)d_in[1];
    const float* tdn  = (const float*)d_in[2];
    const float* basis= (const float*)d_in[3];
    const float* cpl  = (const float*)d_in[4];
    const float* W    = (const float*)d_in[5];
    const float* t_re = (const float*)d_in[6];
    const float* t_im = (const float*)d_in[7];
    const float* g_bu = (const float*)d_in[8];
    const float* g_td = (const float*)d_in[9];
    const float* g_sr = (const float*)d_in[10];
    const float* g_gr = (const float*)d_in[11];
    const float* g_br = (const float*)d_in[12];
    float* out = (float*)d_out;

    char* ws = (char*)d_ws;
    float*          bias   = (float*)(ws);                                    // 64 KB slot
    unsigned short* basisB = (unsigned short*)(ws + (1u << 16));              // 4 MB
    unsigned short* cplT   = (unsigned short*)(ws + (1u << 16) + (4u << 20)); // 1 MB
    unsigned short* b2T    = (unsigned short*)(ws + (1u << 16) + (5u << 20)); // 4 MB
    unsigned short* alpha16= (unsigned short*)(ws + (1u << 16) + (9u << 20)); // 8 MB
    unsigned short* cbuf   = (unsigned short*)(ws + (1u << 16) + (17u << 20));// 8 MB

    k_prep <<<dim3(1280),                  dim3(256), 0, stream>>>(basis, cpl, W, t_re, t_im, g_sr, basisB, cplT, bias);
    k_b2   <<<dim3(M_ / 64, H_ / 128, B_), dim3(256), 0, stream>>>(cplT, basisB, b2T);
    k_alpha<<<dim3(512),                   dim3(256), 0, stream>>>(hs, inc, tdn, bias, g_bu, g_td, b2T, alpha16);
    k_scan <<<dim3(256),                   dim3(256), 0, stream>>>(alpha16, t_re, g_gr, g_br, cbuf);
    k_y    <<<dim3(512),                   dim3(512), 0, stream>>>(cbuf, basisB, out);
}

// Round 11
// 161.634 us; speedup vs baseline: 1.1129x; 1.0155x over previous
//
#include <hip/hip_runtime.h>
#include <hip/hip_bf16.h>

// Sizes fixed by the problem.
#define B_  8
#define T_  2048
#define H_  1024
#define M_  256

typedef __bf16 bf16x8 __attribute__((ext_vector_type(8)));
typedef float  f32x4  __attribute__((ext_vector_type(4)));
typedef unsigned short us4 __attribute__((ext_vector_type(4)));
typedef unsigned short us8 __attribute__((ext_vector_type(8)));

__device__ inline unsigned short f2bf(float f) {
    unsigned int u = __builtin_bit_cast(unsigned int, f);
    return (unsigned short)((u + 0x7FFFu + ((u >> 16) & 1u)) >> 16);
}
__device__ inline float bf2f(unsigned short u) {
    unsigned int x = ((unsigned int)u) << 16;
    return __builtin_bit_cast(float, x);
}

// ---------------------------------------------------------------------------
// K_prep: fused {basis cast, coupling transpose-cast, bias GEMV}.
// grid 1280 x 256
__global__ void k_prep(const float* __restrict__ basis, const float* __restrict__ cpl,
                       const float* __restrict__ W, const float* __restrict__ re,
                       const float* __restrict__ im, const float* __restrict__ g_srg,
                       unsigned short* __restrict__ basisB, unsigned short* __restrict__ cplT,
                       float* __restrict__ bias)
{
    int blk = blockIdx.x;
    int tid = threadIdx.x;
    if (blk < 1024) {
        size_t i = ((size_t)blk * 256 + tid) * 8;
        float4 a = *(const float4*)&basis[i];
        float4 b = *(const float4*)&basis[i + 4];
        us8 o = { f2bf(a.x), f2bf(a.y), f2bf(a.z), f2bf(a.w),
                  f2bf(b.x), f2bf(b.y), f2bf(b.z), f2bf(b.w) };
        *(us8*)&basisB[i] = o;
    } else if (blk < 1152) {
        int idx = blk - 1024;
        int x = idx & 3, y = (idx >> 2) & 3, b = idx >> 4;
        int r0 = x * 64, c0 = y * 64;
        __shared__ float t[64][65];
        #pragma unroll
        for (int i = 0; i < 4; ++i) {
            int u = tid + i * 256;
            int r = u >> 4, c4 = (u & 15) * 4;
            float4 v = *(const float4*)&cpl[((size_t)(b * M_ + r0 + r)) * M_ + c0 + c4];
            t[r][c4] = v.x; t[r][c4 + 1] = v.y; t[r][c4 + 2] = v.z; t[r][c4 + 3] = v.w;
        }
        __syncthreads();
        #pragma unroll
        for (int i = 0; i < 4; ++i) {
            int u = tid + i * 256;
            int m = u >> 4, r4 = (u & 15) * 4;
            us4 o = { f2bf(t[r4][m]), f2bf(t[r4 + 1][m]), f2bf(t[r4 + 2][m]), f2bf(t[r4 + 3][m]) };
            *(us4*)&cplT[((size_t)(b * M_ + c0 + m)) * M_ + r0 + r4] = o;
        }
    } else {
        int idx = blk - 1152;
        int b = idx & 7, h0 = (idx >> 3) * 64;
        int lane = tid & 63, w = tid >> 6;
        int h = h0 + lane;
        float acc = 0.f;
        #pragma unroll 4
        for (int m = w * 64; m < w * 64 + 64; ++m) {
            float rv = re[b * M_ + m], iv = im[b * M_ + m];
            acc += rv * W[(size_t)m * H_ + h] + iv * W[(size_t)(M_ + m) * H_ + h];
        }
        __shared__ float sh[4][64];
        sh[w][lane] = acc;
        __syncthreads();
        if (w == 0)
            bias[b * H_ + h] = g_srg[0] * (sh[0][lane] + sh[1][lane] + sh[2][lane] + sh[3][lane]);
    }
}

// ---------------------------------------------------------------------------
// K1b: b2T[b][n][h] = sum_mp cplT[b][n][mp] * basisB[b][h][mp]   (bf16 MFMA GEMM)
__global__ __launch_bounds__(256) void k_b2(const unsigned short* __restrict__ cplT,
                                            const unsigned short* __restrict__ basisB,
                                            unsigned short* __restrict__ b2T)
{
    const int b = blockIdx.z;
    const int n0 = blockIdx.x * 64;
    const int h0 = blockIdx.y * 128;
    const int tid = threadIdx.x;
    const int lane = tid & 63, w = tid >> 6;

    __shared__ __align__(16) unsigned short As[64][72];
    __shared__ __align__(16) unsigned short Bs[128][72];

    const unsigned short* Ab = cplT + (size_t)(b * M_ + n0) * M_;
    const unsigned short* Bb = basisB + (size_t)(b * H_ + h0) * M_;

    f32x4 acc[4][2];
    #pragma unroll
    for (int i = 0; i < 4; ++i) { acc[i][0] = (f32x4){0,0,0,0}; acc[i][1] = (f32x4){0,0,0,0}; }

    const int rsel = lane & 15;
    const int kgrp = (lane >> 4) * 8;

    for (int k0 = 0; k0 < M_; k0 += 64) {
        #pragma unroll
        for (int i = 0; i < 2; ++i) {
            int u = tid + i * 256;
            int r = u >> 3, c8 = (u & 7) * 8;
            *(us8*)&As[r][c8] = *(const us8*)&Ab[(size_t)r * M_ + k0 + c8];
        }
        #pragma unroll
        for (int i = 0; i < 4; ++i) {
            int u = tid + i * 256;
            int r = u >> 3, c8 = (u & 7) * 8;
            *(us8*)&Bs[r][c8] = *(const us8*)&Bb[(size_t)r * M_ + k0 + c8];
        }
        __syncthreads();
        #pragma unroll
        for (int kk = 0; kk < 2; ++kk) {
            const int kb = kk * 32 + kgrp;
            bf16x8 af[4], bfr[2];
            #pragma unroll
            for (int mi = 0; mi < 4; ++mi) af[mi] = *(const bf16x8*)&As[mi * 16 + rsel][kb];
            #pragma unroll
            for (int ni = 0; ni < 2; ++ni) bfr[ni] = *(const bf16x8*)&Bs[w * 32 + ni * 16 + rsel][kb];
            #pragma unroll
            for (int mi = 0; mi < 4; ++mi)
                #pragma unroll
                for (int ni = 0; ni < 2; ++ni)
                    acc[mi][ni] = __builtin_amdgcn_mfma_f32_16x16x32_bf16(af[mi], bfr[ni], acc[mi][ni], 0, 0, 0);
        }
        __syncthreads();
    }

    unsigned short* ob = b2T + (size_t)(b * M_ + n0) * H_ + h0;
    const int rbase = (lane >> 4) * 4;
    #pragma unroll
    for (int mi = 0; mi < 4; ++mi)
        #pragma unroll
        for (int ni = 0; ni < 2; ++ni)
            #pragma unroll
            for (int r = 0; r < 4; ++r)
                ob[(size_t)(mi * 16 + rbase + r) * H_ + w * 32 + ni * 16 + rsel] = f2bf(acc[mi][ni][r]);
}

// ---------------------------------------------------------------------------
// K2 (FUSED gate+alpha): alpha16 = bf16(hs + bu*inc + td*tdn + bias) @ b2.
// 512 threads / 8 waves; BM=32, full-K 64KB LDS A-tile, ONE barrier.
// Stage: 16 iters x 2 rows (coalesced float4 x3 streams), bias loaded once.
// MFMA: wave owns a 32-m slice (acc[2][2], 128 MFMAs); B gathered from
// XCD-resident b2T (batch = blk&7). __launch_bounds__(512,4) -> 2 blocks/CU
// = 16 waves/CU (2x round-10 MLP).
__global__ __launch_bounds__(512, 4) void k_alpha(
    const float* __restrict__ hs, const float* __restrict__ inc, const float* __restrict__ tdn,
    const float* __restrict__ bias, const float* __restrict__ g_bu, const float* __restrict__ g_td,
    const unsigned short* __restrict__ b2T, unsigned short* __restrict__ alpha16)
{
    const int flat = blockIdx.x;
    const int b = flat & 7;
    const int t0 = (flat >> 3) * 32;
    const int tid = threadIdx.x;
    const int lane = tid & 63, wid = tid >> 6;

    __shared__ __align__(16) unsigned short As[32 * 1024];   // 64 KB, swizzled

    const float bug = g_bu[0], tdg = g_td[0];
    const int col = (tid & 255) * 4;          // 0..1020, fixed per thread
    const int r0 = tid >> 8;                  // 0 or 1
    const size_t rb = ((size_t)(b * T_) + t0 + r0) * H_ + col;
    const float* hs0 = hs + rb;
    const float* in0 = inc + rb;
    const float* td0 = tdn + rb;
    f32x4 bi = *(const f32x4*)(bias + b * H_ + col);   // loaded once

    #pragma unroll 8
    for (int it = 0; it < 16; ++it) {
        int row = it * 2 + r0;
        f32x4 a = *(const f32x4*)(hs0 + (size_t)(it * 2) * H_);
        f32x4 e = *(const f32x4*)(in0 + (size_t)(it * 2) * H_);
        f32x4 d = *(const f32x4*)(td0 + (size_t)(it * 2) * H_);
        f32x4 c = a + bug * e + tdg * d + bi;
        us4 o = { f2bf(c[0]), f2bf(c[1]), f2bf(c[2]), f2bf(c[3]) };
        int sw = ((((col >> 3) ^ (row & 7)) << 3) | (col & 7));
        *(us4*)&As[row * 1024 + sw] = o;
    }
    __syncthreads();

    const int rsel = lane & 15;
    const int kgo = (lane >> 4) * 8;
    const int rswz = rsel & 7;
    const unsigned short* As0 = &As[rsel * 1024];
    const unsigned short* As1 = &As[(16 + rsel) * 1024];
    const unsigned short* Bb = b2T + ((size_t)(b * M_) + wid * 32 + rsel) * H_ + kgo;

    f32x4 acc[2][2];
    acc[0][0] = (f32x4){0,0,0,0}; acc[0][1] = (f32x4){0,0,0,0};
    acc[1][0] = (f32x4){0,0,0,0}; acc[1][1] = (f32x4){0,0,0,0};

    #pragma unroll 4
    for (int kc = 0; kc < 32; ++kc) {
        int cA = kc * 32 + kgo;
        int sw = ((((cA) >> 3) ^ rswz) << 3);
        bf16x8 af0 = *(const bf16x8*)&As0[sw];
        bf16x8 af1 = *(const bf16x8*)&As1[sw];
        #pragma unroll
        for (int ni = 0; ni < 2; ++ni) {
            bf16x8 bv = *(const bf16x8*)(Bb + (size_t)ni * (16 * H_) + kc * 32);
            acc[0][ni] = __builtin_amdgcn_mfma_f32_16x16x32_bf16(af0, bv, acc[0][ni], 0, 0, 0);
            acc[1][ni] = __builtin_amdgcn_mfma_f32_16x16x32_bf16(af1, bv, acc[1][ni], 0, 0, 0);
        }
    }

    unsigned short* ab = alpha16 + ((size_t)(b * T_) + t0) * M_ + wid * 32;
    const int rbase = (lane >> 4) * 4;
    #pragma unroll
    for (int mi = 0; mi < 2; ++mi)
        #pragma unroll
        for (int ni = 0; ni < 2; ++ni)
            #pragma unroll
            for (int r = 0; r < 4; ++r)
                ab[(size_t)(mi * 16 + rbase + r) * M_ + ni * 16 + rsel] = f2bf(acc[mi][ni][r]);
}

// ---------------------------------------------------------------------------
// K3: chunked-parallel scan, chunk=64, halo=96 (gamma^96 ~ 4e-5)
// grid 256 flat (batch-per-XCD), block 256 (= m)
__global__ void k_scan(const unsigned short* __restrict__ alpha16, const float* __restrict__ tape_re,
                       const float* __restrict__ g_gr, const float* __restrict__ g_br,
                       unsigned short* __restrict__ cbuf)
{
    int flat = blockIdx.x;
    int b = flat & 7, chunk = flat >> 3;
    int m = threadIdx.x;
    float graw = g_gr[0], braw = g_br[0];
    float gamma = 1.f / (1.f + __expf(-graw));
    float beta  = log1pf(__expf(braw));
    int t0 = chunk * 64;
    int th = (t0 >= 96) ? (t0 - 96) : 0;
    float s = tape_re[b * M_ + m];
    if (th > 0) s *= __powf(gamma, (float)th);
    const unsigned short* ab = alpha16 + (size_t)b * T_ * M_ + m;
    unsigned short* cb = cbuf + (size_t)b * T_ * M_ + m;
    #pragma unroll 4
    for (int t = th; t < t0 + 64; ++t) {
        float a = bf2f(ab[(size_t)t * M_]);
        s = gamma * s + beta * a;
        if (t >= t0) cb[(size_t)t * M_] = f2bf(a * s);
    }
}

// ---------------------------------------------------------------------------
// K4: y = c @ basis^T. Single-barrier full-K template: A = cbuf tile
// 32x256 in LDS (16KB, XOR-swizzle), B = basisB gathered from XCD-resident L2.
// 8 waves (h-slice of 128 each), grid 512 flat, 2 blocks/CU. Write-bound.
__global__ __launch_bounds__(512, 4) void k_y(const unsigned short* __restrict__ cbuf,
                                              const unsigned short* __restrict__ basisB,
                                              float* __restrict__ out)
{
    const int flat = blockIdx.x;
    const int b = flat & 7;
    const int t0 = (flat >> 3) * 32;
    const int tid = threadIdx.x;
    const int lane = tid & 63, wid = tid >> 6;

    __shared__ __align__(16) unsigned short As[32 * 256];    // 16 KB, swizzled

    const unsigned short* src = cbuf + ((size_t)(b * T_) + t0) * M_;
    #pragma unroll
    for (int i = 0; i < 2; ++i) {
        int e = i * 4096 + tid * 8;          // 512 thr x 8 = 4096 per iter
        int row = e >> 8;
        int col = e & 255;
        int sw = (((col >> 3) ^ (row & 7)) << 3);
        *(us8*)&As[row * 256 + sw] = *(const us8*)&src[e];
    }
    __syncthreads();

    const int rsel = lane & 15;
    const int kgo = (lane >> 4) * 8;
    const int rswz = rsel & 7;
    const unsigned short* As0 = &As[rsel * 256];
    const unsigned short* As1 = &As[(16 + rsel) * 256];
    const unsigned short* Bh = basisB + ((size_t)(b * H_) + wid * 128 + rsel) * M_ + kgo;

    f32x4 acc[2][8];
    #pragma unroll
    for (int i = 0; i < 2; ++i)
        #pragma unroll
        for (int j = 0; j < 8; ++j)
            acc[i][j] = (f32x4){0.f, 0.f, 0.f, 0.f};

    #pragma unroll 2
    for (int kc = 0; kc < 8; ++kc) {
        int cA = kc * 32 + kgo;
        int sw = ((((cA) >> 3) ^ rswz) << 3);
        bf16x8 af0 = *(const bf16x8*)&As0[sw];
        bf16x8 af1 = *(const bf16x8*)&As1[sw];
        #pragma unroll
        for (int ni = 0; ni < 8; ++ni) {
            bf16x8 bv = *(const bf16x8*)(Bh + (size_t)ni * (16 * M_) + kc * 32);
            acc[0][ni] = __builtin_amdgcn_mfma_f32_16x16x32_bf16(af0, bv, acc[0][ni], 0, 0, 0);
            acc[1][ni] = __builtin_amdgcn_mfma_f32_16x16x32_bf16(af1, bv, acc[1][ni], 0, 0, 0);
        }
    }

    float* ob = out + ((size_t)(b * T_) + t0) * H_ + wid * 128;
    const int rbase = (lane >> 4) * 4;
    #pragma unroll
    for (int mi = 0; mi < 2; ++mi)
        #pragma unroll
        for (int ni = 0; ni < 8; ++ni)
            #pragma unroll
            for (int r = 0; r < 4; ++r)
                ob[(size_t)(mi * 16 + rbase + r) * H_ + ni * 16 + rsel] = acc[mi][ni][r];
}

// ---------------------------------------------------------------------------
extern "C" void kernel_launch(void* const* d_in, const int* in_sizes, int n_in,
                              void* d_out, int out_size, void* d_ws, size_t ws_size,
                              hipStream_t stream)
{
    const float* hs   = (const float*)d_in[0];
    const float* inc  = (const float*)d_in[1];
    const float* tdn  = (const float*)d_in[2];
    const float* basis= (const float*)d_in[3];
    const float* cpl  = (const float*)d_in[4];
    const float* W    = (const float*)d_in[5];
    const float* t_re = (const float*)d_in[6];
    const float* t_im = (const float*)d_in[7];
    const float* g_bu = (const float*)d_in[8];
    const float* g_td = (const float*)d_in[9];
    const float* g_sr = (const float*)d_in[10];
    const float* g_gr = (const float*)d_in[11];
    const float* g_br = (const float*)d_in[12];
    float* out = (float*)d_out;

    char* ws = (char*)d_ws;
    float*          bias   = (float*)(ws);                                    // 64 KB slot
    unsigned short* basisB = (unsigned short*)(ws + (1u << 16));              // 4 MB
    unsigned short* cplT   = (unsigned short*)(ws + (1u << 16) + (4u << 20)); // 1 MB
    unsigned short* b2T    = (unsigned short*)(ws + (1u << 16) + (5u << 20)); // 4 MB
    unsigned short* alpha16= (unsigned short*)(ws + (1u << 16) + (9u << 20)); // 8 MB
    unsigned short* cbuf   = (unsigned short*)(ws + (1u << 16) + (17u << 20));// 8 MB

    k_prep <<<dim3(1280),                  dim3(256), 0, stream>>>(basis, cpl, W, t_re, t_im, g_sr, basisB, cplT, bias);
    k_b2   <<<dim3(M_ / 64, H_ / 128, B_), dim3(256), 0, stream>>>(cplT, basisB, b2T);
    k_alpha<<<dim3(512),                   dim3(512), 0, stream>>>(hs, inc, tdn, bias, g_bu, g_td, b2T, alpha16);
    k_scan <<<dim3(256),                   dim3(256), 0, stream>>>(alpha16, t_re, g_gr, g_br, cbuf);
    k_y    <<<dim3(512),                   dim3(512), 0, stream>>>(cbuf, basisB, out);
}